// Round 4
// baseline (239.243 us; speedup 1.0000x reference)
//
#include <hip/hip_runtime.h>
#include <math.h>

#define LOG2E 1.44269504f

typedef unsigned short us;
typedef __attribute__((ext_vector_type(8))) short bf16x8;
typedef __attribute__((ext_vector_type(4))) float f32x4;
typedef __attribute__((ext_vector_type(16))) float f32x16;

static __device__ __forceinline__ us f2bf(float f) {  // RNE
  union { float f; unsigned u; } v; v.f = f;
  unsigned r = v.u + 0x7fffu + ((v.u >> 16) & 1u);
  return (us)(r >> 16);
}

// ---------------------------------------------------------------------------
// wrep_kernel: weight repack only (tiny).
//   wqc[oc][t*256+ic] = wq[oc][ic][t]*LOG2E ; wkc same (no scale) ; wvb bf16.
// ---------------------------------------------------------------------------
__global__ __launch_bounds__(256) void wrep_kernel(
    const float* __restrict__ wq, const float* __restrict__ wk,
    const float* __restrict__ wv, us* __restrict__ wqc, us* __restrict__ wkc,
    us* __restrict__ wvb) {
  int idx = blockIdx.x * 256 + threadIdx.x;
  if (idx < 24576) {
    int oc = idx / 768, r = idx % 768, t = r >> 8, ic = r & 255;
    wqc[idx] = f2bf(wq[(oc * 256 + ic) * 3 + t] * LOG2E);
  } else if (idx < 49152) {
    int j = idx - 24576;
    int oc = j / 768, r = j % 768, t = r >> 8, ic = r & 255;
    wkc[j] = f2bf(wk[(oc * 256 + ic) * 3 + t]);
  } else if (idx < 114688) {
    int j = idx - 49152;
    wvb[j] = f2bf(wv[j]);
  }
}

// ---------------------------------------------------------------------------
// fconv_kernel: fused transpose + q/k/v convs. One block per (b, 128-row
// tile): 256 blocks x 1024 thr, 128KB LDS, 1 block/CU, single round.
//   Stage 1 (all 16 waves): load x rows n0-64..n0+127 (halo for k's (3,1)
//   kernel; out-of-range rows -> 0 = conv zero-padding), f32 -> bf16
//   (v_cvt_pk pairs), into LDS xs[256 rows][256 c] with 16B-chunk XOR
//   swizzle  chunk' = (c>>3) ^ (row&31)  — conflict-free for both the b32
//   transpose writes (32 distinct chunks across lane&31) and the stride-
//   512B ds_read_b128 B-frag reads (16 distinct chunks per quad-group).
//   Stage 2: waves 0-3 q-conv (dn=t-1, W-edge lanes zeroed), waves 4-7
//   k-conv (dn=(t-1)*64, halo zeros ARE the padding), waves 8-15 v-conv
//   (1x1). Outputs qT/kT[b][n][oc] and vblk[b][n>>4][oc][n&15] — formats
//   identical to before; attn kernel unchanged.
// ---------------------------------------------------------------------------
__global__ __launch_bounds__(1024) void fconv_kernel(
    const float* __restrict__ x, const us* __restrict__ wqc,
    const us* __restrict__ wkc, const float* __restrict__ bq,
    const float* __restrict__ bk, const us* __restrict__ wvb,
    const float* __restrict__ bv, us* __restrict__ qT, us* __restrict__ kT,
    us* __restrict__ vblk) {
  __shared__ __align__(16) us xs[256 * 256];  // 128KB, swizzled [rr][c]

  int tid = threadIdx.x, lane = tid & 63, w = tid >> 6;
  int l15 = lane & 15, quad = lane >> 4;
  int bid = blockIdx.x;
  int b = bid >> 5, yt = bid & 31;
  int no0 = yt * 128;  // first own row (global n) of this block
  const float* xb = x + ((size_t)b << 20);

  // ---- stage 1: transpose into swizzled LDS ----
  // wave w: c-pairs cp = w*8+i (c = 2cp, 2cp+1); rows rr = rb*64 + lane.
#pragma unroll
  for (int i = 0; i < 8; i++) {
    int c0 = (w * 8 + i) * 2;
    const float* xc0 = xb + ((size_t)c0 << 12);
#pragma unroll
    for (int rb = 0; rb < 4; rb++) {
      int rr = rb * 64 + lane;
      int gn = no0 - 64 + rr;
      bool valid = (unsigned)gn < 4096u;
      float a0 = valid ? xc0[gn] : 0.f;
      float a1 = valid ? xc0[4096 + gn] : 0.f;
      unsigned u;
      asm("v_cvt_pk_bf16_f32 %0, %1, %2" : "=v"(u) : "v"(a0), "v"(a1));
      int chunk = (c0 >> 3) ^ (rr & 31);
      *(unsigned*)&xs[rr * 256 + chunk * 8 + (c0 & 7)] = u;
    }
  }
  __syncthreads();

  // ---- stage 2: convs from LDS ----
  if (w < 8) {
    // q (waves 0-3) / k (waves 4-7): K=768 im2col GEMM, 2 oc-tiles x 2 n-tiles
    bool isq = (w < 4);
    int qw = isq ? w : (w - 4);
    const us* wc = isq ? wqc : wkc;
    f32x4 acc00 = (f32x4){0.f, 0.f, 0.f, 0.f}, acc01 = acc00;
    f32x4 acc10 = acc00, acc11 = acc00;
#pragma unroll
    for (int t = 0; t < 3; t++) {
      int dn = isq ? (t - 1) : (t - 1) * 64;
#pragma unroll
      for (int k8 = 0; k8 < 8; k8++) {
        int kloc = t * 256 + k8 * 32 + quad * 8;
        bf16x8 af0 = *(const bf16x8*)(wc + (size_t)l15 * 768 + kloc);
        bf16x8 af1 = *(const bf16x8*)(wc + (size_t)(16 + l15) * 768 + kloc);
        int cb3 = (k8 * 32 + quad * 8) >> 3;
#pragma unroll
        for (int j = 0; j < 2; j++) {
          int ntl = (qw * 2 + j) * 16 + l15;
          int rr = 64 + ntl + dn;
          bf16x8 bf = *(const bf16x8*)&xs[rr * 256 + ((cb3 ^ (rr & 31)) << 3)];
          if (isq && ((t == 0 && (ntl & 63) == 0) || (t == 2 && (ntl & 63) == 63)))
            bf = (bf16x8){0, 0, 0, 0, 0, 0, 0, 0};
          if (j == 0) {
            acc00 = __builtin_amdgcn_mfma_f32_16x16x32_bf16(af0, bf, acc00, 0, 0, 0);
            acc10 = __builtin_amdgcn_mfma_f32_16x16x32_bf16(af1, bf, acc10, 0, 0, 0);
          } else {
            acc01 = __builtin_amdgcn_mfma_f32_16x16x32_bf16(af0, bf, acc01, 0, 0, 0);
            acc11 = __builtin_amdgcn_mfma_f32_16x16x32_bf16(af1, bf, acc11, 0, 0, 0);
          }
        }
      }
    }
    const float* bias = isq ? bq : bk;
    float bsc = isq ? LOG2E : 1.0f;
    us* outp = (isq ? qT : kT) + (((size_t)b << 12) * 32);
#pragma unroll
    for (int mo = 0; mo < 2; mo++) {
      float b0 = bias[mo * 16 + quad * 4 + 0] * bsc;
      float b1 = bias[mo * 16 + quad * 4 + 1] * bsc;
      float b2 = bias[mo * 16 + quad * 4 + 2] * bsc;
      float b3 = bias[mo * 16 + quad * 4 + 3] * bsc;
#pragma unroll
      for (int j = 0; j < 2; j++) {
        f32x4 a = (mo == 0) ? (j == 0 ? acc00 : acc01) : (j == 0 ? acc10 : acc11);
        int n = no0 + (qw * 2 + j) * 16 + l15;
        unsigned lo = (unsigned)f2bf(a[0] + b0) | ((unsigned)f2bf(a[1] + b1) << 16);
        unsigned hi = (unsigned)f2bf(a[2] + b2) | ((unsigned)f2bf(a[3] + b3) << 16);
        *(uint2*)(outp + (size_t)n * 32 + mo * 16 + quad * 4) = make_uint2(lo, hi);
      }
    }
  } else {
    // v conv (waves 8-15): one 16-row n-tile each, all 256 oc
    int nt = w - 8;
    int rr = 64 + nt * 16 + l15;
    f32x4 acc[16];
#pragma unroll
    for (int ot = 0; ot < 16; ot++) acc[ot] = (f32x4){0.f, 0.f, 0.f, 0.f};
#pragma unroll
    for (int kk = 0; kk < 8; kk++) {
      int cb3 = (kk * 32 + quad * 8) >> 3;
      bf16x8 bfr = *(const bf16x8*)&xs[rr * 256 + ((cb3 ^ (rr & 31)) << 3)];
#pragma unroll
      for (int ot = 0; ot < 16; ot++) {
        bf16x8 af = *(const bf16x8*)(wvb + (size_t)(ot * 16 + l15) * 256 + kk * 32 + quad * 8);
        acc[ot] = __builtin_amdgcn_mfma_f32_16x16x32_bf16(af, bfr, acc[ot], 0, 0, 0);
      }
    }
    us* vb = vblk + ((size_t)b << 20);
    int n16 = yt * 8 + nt;
#pragma unroll
    for (int ot = 0; ot < 16; ot++) {
#pragma unroll
      for (int r = 0; r < 4; r++) {
        int oc = ot * 16 + quad * 4 + r;
        vb[((size_t)n16 * 256 + oc) * 16 + l15] = f2bf(acc[ot][r] + bv[oc]);
      }
    }
  }
}

// ---------------------------------------------------------------------------
// Flash attention (unchanged from R3): no-max softmax, swapped QK mfma(k,q),
// packed cvt_pk P-writes, T15 reorder (softmax(n) after PV(n-1)), register
// ping-pong K (period 2) / V (period 4), lgkmcnt-only barrier drain.
// ---------------------------------------------------------------------------
__global__ __launch_bounds__(512, 4) void attn_kernel(
    const float* __restrict__ x, const us* __restrict__ qT,
    const us* __restrict__ kT, const us* __restrict__ vblk,
    const float* __restrict__ gamma_p, float* __restrict__ out) {
  __shared__ __align__(16) us pb[2][64 * 72];  // [i][j], stride 72
  __shared__ float lpart[2][64];

  int tid = threadIdx.x, lane = tid & 63, w = tid >> 6;
  int l15 = lane & 15, quad = lane >> 4;
  int l31 = lane & 31, h32 = lane >> 5;
  int tw = w & 3, jh = w >> 2;

  int bid = blockIdx.x;
  int b = bid & 7, i0 = (bid >> 3) * 64;

  const us* qTb = qT + (((size_t)b << 12) * 32);
  const us* kTb = kT + (((size_t)b << 12) * 32);
  const us* vbb = vblk + ((size_t)b << 20);

  bf16x8 qf = *(const bf16x8*)(qTb + (size_t)(i0 + tw * 16 + l15) * 32 + quad * 8);

  const us* kbase = kTb + (size_t)(jh * 32 + l15) * 32 + quad * 8;   // +jt*2048
  const us* vbase = vbb + (size_t)(w * 32 + l31) * 16 + h32 * 8;     // +jt*16384
  int pwi = (tw * 16 + l15) * 72 + jh * 32 + quad * 4;
  int pri = l31 * 72 + h32 * 8;

  float lr = 0.f;
  f32x4 s0, s1;
  f32x16 o0, o1;
#pragma unroll
  for (int rg = 0; rg < 16; rg++) { o0[rg] = 0.f; o1[rg] = 0.f; }

  bf16x8 kS0a, kS0b, kS1a, kS1b;
  bf16x8 v0_0, v0_1, v0_2, v0_3;
  bf16x8 v1_0, v1_1, v1_2, v1_3;
  bf16x8 v2_0, v2_1, v2_2, v2_3;
  bf16x8 v3_0, v3_1, v3_2, v3_3;

#define PRE(JT, KN0, KN1, VN0, VN1, VN2, VN3)                                  \
  do {                                                                         \
    int jn = (JT) & 63;                                                        \
    const us* kp = kbase + (size_t)jn * 2048;                                  \
    const us* vp = vbase + (size_t)jn * 16384;                                 \
    KN0 = *(const bf16x8*)(kp);                                                \
    KN1 = *(const bf16x8*)(kp + 512);                                          \
    VN0 = *(const bf16x8*)(vp);                                                \
    VN1 = *(const bf16x8*)(vp + 4096);                                         \
    VN2 = *(const bf16x8*)(vp + 8192);                                         \
    VN3 = *(const bf16x8*)(vp + 12288);                                        \
  } while (0)

#define QKM(KC0, KC1)                                                          \
  do {                                                                         \
    s0 = __builtin_amdgcn_mfma_f32_16x16x32_bf16(KC0, qf, (f32x4){0.f, 0.f, 0.f, 0.f}, 0, 0, 0); \
    s1 = __builtin_amdgcn_mfma_f32_16x16x32_bf16(KC1, qf, (f32x4){0.f, 0.f, 0.f, 0.f}, 0, 0, 0); \
  } while (0)

#define PVM(BUFR, VP0, VP1, VP2, VP3)                                          \
  do {                                                                         \
    const us* pr = (const us*)pb + (BUFR) * (64 * 72) + pri;                   \
    __builtin_amdgcn_s_setprio(1);                                             \
    bf16x8 pf0, pf1;                                                           \
    pf0 = *(const bf16x8*)(pr + 0);                                            \
    pf1 = *(const bf16x8*)(pr + 32 * 72 + 0);                                  \
    o0 = __builtin_amdgcn_mfma_f32_32x32x16_bf16(VP0, pf0, o0, 0, 0, 0);       \
    o1 = __builtin_amdgcn_mfma_f32_32x32x16_bf16(VP0, pf1, o1, 0, 0, 0);       \
    pf0 = *(const bf16x8*)(pr + 16);                                           \
    pf1 = *(const bf16x8*)(pr + 32 * 72 + 16);                                 \
    o0 = __builtin_amdgcn_mfma_f32_32x32x16_bf16(VP1, pf0, o0, 0, 0, 0);       \
    o1 = __builtin_amdgcn_mfma_f32_32x32x16_bf16(VP1, pf1, o1, 0, 0, 0);       \
    pf0 = *(const bf16x8*)(pr + 32);                                           \
    pf1 = *(const bf16x8*)(pr + 32 * 72 + 32);                                 \
    o0 = __builtin_amdgcn_mfma_f32_32x32x16_bf16(VP2, pf0, o0, 0, 0, 0);       \
    o1 = __builtin_amdgcn_mfma_f32_32x32x16_bf16(VP2, pf1, o1, 0, 0, 0);       \
    pf0 = *(const bf16x8*)(pr + 48);                                           \
    pf1 = *(const bf16x8*)(pr + 32 * 72 + 48);                                 \
    o0 = __builtin_amdgcn_mfma_f32_32x32x16_bf16(VP3, pf0, o0, 0, 0, 0);       \
    o1 = __builtin_amdgcn_mfma_f32_32x32x16_bf16(VP3, pf1, o1, 0, 0, 0);       \
    __builtin_amdgcn_s_setprio(0);                                             \
  } while (0)

#define SMW(BUFW)                                                              \
  do {                                                                         \
    us* pw = (us*)pb + (BUFW) * (64 * 72) + pwi;                               \
    {                                                                          \
      float p0 = __builtin_amdgcn_exp2f(s0[0]);                                \
      float p1 = __builtin_amdgcn_exp2f(s0[1]);                                \
      float p2 = __builtin_amdgcn_exp2f(s0[2]);                                \
      float p3 = __builtin_amdgcn_exp2f(s0[3]);                                \
      lr += (p0 + p1) + (p2 + p3);                                             \
      unsigned e0, e1;                                                         \
      asm("v_cvt_pk_bf16_f32 %0, %1, %2" : "=v"(e0) : "v"(p0), "v"(p1));       \
      asm("v_cvt_pk_bf16_f32 %0, %1, %2" : "=v"(e1) : "v"(p2), "v"(p3));       \
      *(uint2*)pw = make_uint2(e0, e1);                                        \
    }                                                                          \
    {                                                                          \
      float p0 = __builtin_amdgcn_exp2f(s1[0]);                                \
      float p1 = __builtin_amdgcn_exp2f(s1[1]);                                \
      float p2 = __builtin_amdgcn_exp2f(s1[2]);                                \
      float p3 = __builtin_amdgcn_exp2f(s1[3]);                                \
      lr += (p0 + p1) + (p2 + p3);                                             \
      unsigned e0, e1;                                                         \
      asm("v_cvt_pk_bf16_f32 %0, %1, %2" : "=v"(e0) : "v"(p0), "v"(p1));       \
      asm("v_cvt_pk_bf16_f32 %0, %1, %2" : "=v"(e1) : "v"(p2), "v"(p3));       \
      *(uint2*)(pw + 16) = make_uint2(e0, e1);                                 \
    }                                                                          \
  } while (0)

#define BAR                                                                    \
  do {                                                                         \
    asm volatile("s_waitcnt lgkmcnt(0)" ::: "memory");                         \
    __builtin_amdgcn_s_barrier();                                              \
    __builtin_amdgcn_sched_barrier(0);                                         \
  } while (0)

  PRE(0, kS0a, kS0b, v0_0, v0_1, v0_2, v0_3);
  PRE(1, kS1a, kS1b, v1_0, v1_1, v1_2, v1_3);
  QKM(kS0a, kS0b);
  SMW(0);
  BAR;
  PRE(2, kS0a, kS0b, v2_0, v2_1, v2_2, v2_3);
  QKM(kS1a, kS1b);
  PVM(0, v0_0, v0_1, v0_2, v0_3);
  SMW(1);
  BAR;
  PRE(3, kS1a, kS1b, v3_0, v3_1, v3_2, v3_3);
  QKM(kS0a, kS0b);
  PVM(1, v1_0, v1_1, v1_2, v1_3);
  SMW(0);
  BAR;
  PRE(4, kS0a, kS0b, v0_0, v0_1, v0_2, v0_3);
  QKM(kS1a, kS1b);
  PVM(0, v2_0, v2_1, v2_2, v2_3);
  SMW(1);
  BAR;

  for (int n4 = 1; n4 < 16; n4++) {
    int n = n4 * 4;
    PRE(n + 1, kS1a, kS1b, v1_0, v1_1, v1_2, v1_3);
    QKM(kS0a, kS0b);
    PVM(1, v3_0, v3_1, v3_2, v3_3);
    SMW(0);
    BAR;
    PRE(n + 2, kS0a, kS0b, v2_0, v2_1, v2_2, v2_3);
    QKM(kS1a, kS1b);
    PVM(0, v0_0, v0_1, v0_2, v0_3);
    SMW(1);
    BAR;
    PRE(n + 3, kS1a, kS1b, v3_0, v3_1, v3_2, v3_3);
    QKM(kS0a, kS0b);
    PVM(1, v1_0, v1_1, v1_2, v1_3);
    SMW(0);
    BAR;
    PRE(n + 4, kS0a, kS0b, v0_0, v0_1, v0_2, v0_3);
    QKM(kS1a, kS1b);
    PVM(0, v2_0, v2_1, v2_2, v2_3);
    SMW(1);
    BAR;
  }
  PVM(1, v3_0, v3_1, v3_2, v3_3);

#undef PRE
#undef QKM
#undef PVM
#undef SMW
#undef BAR

  float lt = lr;
  lt += __shfl_xor(lt, 16);
  lt += __shfl_xor(lt, 32);
  if (quad == 0) lpart[jh][tw * 16 + l15] = lt;
  __syncthreads();
  float g = gamma_p[0];
  const float* xb = x + ((size_t)b << 20);
  float* ob = out + ((size_t)b << 20);
  float gl[2];
#pragma unroll
  for (int it = 0; it < 2; it++) {
    int i = it * 32 + l31;
    gl[it] = g / (lpart[0][i] + lpart[1][i]);
  }
#pragma unroll
  for (int it = 0; it < 2; it++) {
    int i = i0 + it * 32 + l31;
    const f32x16& o = (it == 0) ? o0 : o1;
#pragma unroll
    for (int rg = 0; rg < 16; rg++) {
      int c = w * 32 + ((rg & 3) + 8 * (rg >> 2) + 4 * h32);
      size_t idx = ((size_t)c << 12) + i;
      ob[idx] = o[rg] * gl[it] + xb[idx];
    }
  }
}

// ---------------------------------------------------------------------------
extern "C" void kernel_launch(void* const* d_in, const int* in_sizes, int n_in,
                              void* d_out, int out_size, void* d_ws, size_t ws_size,
                              hipStream_t stream) {
  const float* x = (const float*)d_in[0];
  const float* wq = (const float*)d_in[1];
  const float* bq = (const float*)d_in[2];
  const float* wk = (const float*)d_in[3];
  const float* bk = (const float*)d_in[4];
  const float* wv = (const float*)d_in[5];
  const float* bv = (const float*)d_in[6];
  const float* gamma = (const float*)d_in[7];
  float* out = (float*)d_out;

  us* qT = (us*)d_ws;                 // 1,048,576 us
  us* kT = qT + (size_t)1048576;      // 1,048,576
  us* vblk = kT + (size_t)1048576;    // 8,388,608
  us* wqc = vblk + (size_t)8388608;   // 24,576
  us* wkc = wqc + (size_t)24576;      // 24,576
  us* wvb = wkc + (size_t)24576;      // 65,536

  wrep_kernel<<<448, 256, 0, stream>>>(wq, wk, wv, wqc, wkc, wvb);
  fconv_kernel<<<256, 1024, 0, stream>>>(x, wqc, wkc, bq, bk, wvb, bv, qT, kT, vblk);
  attn_kernel<<<512, 512, 0, stream>>>(x, qT, kT, vblk, gamma, out);
}

// Round 5
// 235.761 us; speedup vs baseline: 1.0148x; 1.0148x over previous
//
#include <hip/hip_runtime.h>
#include <math.h>

#define LOG2E 1.44269504f

typedef unsigned short us;
typedef __attribute__((ext_vector_type(8))) short bf16x8;
typedef __attribute__((ext_vector_type(4))) float f32x4;
typedef __attribute__((ext_vector_type(16))) float f32x16;

static __device__ __forceinline__ us f2bf(float f) {  // RNE
  union { float f; unsigned u; } v; v.f = f;
  unsigned r = v.u + 0x7fffu + ((v.u >> 16) & 1u);
  return (us)(r >> 16);
}

// ---------------------------------------------------------------------------
// wrep_kernel: weight repack only (tiny).
// ---------------------------------------------------------------------------
__global__ __launch_bounds__(256) void wrep_kernel(
    const float* __restrict__ wq, const float* __restrict__ wk,
    const float* __restrict__ wv, us* __restrict__ wqc, us* __restrict__ wkc,
    us* __restrict__ wvb) {
  int idx = blockIdx.x * 256 + threadIdx.x;
  if (idx < 24576) {
    int oc = idx / 768, r = idx % 768, t = r >> 8, ic = r & 255;
    wqc[idx] = f2bf(wq[(oc * 256 + ic) * 3 + t] * LOG2E);
  } else if (idx < 49152) {
    int j = idx - 24576;
    int oc = j / 768, r = j % 768, t = r >> 8, ic = r & 255;
    wkc[j] = f2bf(wk[(oc * 256 + ic) * 3 + t]);
  } else if (idx < 114688) {
    int j = idx - 49152;
    wvb[j] = f2bf(wv[j]);
  }
}

// ---------------------------------------------------------------------------
// fconv_kernel: fused transpose + q/k/v convs. One block per (b, 128-row
// tile): 256 blocks x 1024 thr, 128KB LDS, 1 block/CU.
//   XCD remap: b = hw&7, yt = hw>>3 -> each XCD owns one batch; x(b)=4MB
//   fits its L2, halo rows shared between neighbor tiles hit L2 not HBM.
//   Stage 1: task=(rr, cw 8-chan chunk): 8 wave-coalesced f32 loads,
//   4 cvt_pk, ONE ds_write_b128 at swizzled chunk cw^(rr&31). b128 writes
//   are bank-uniform (R4's b32 writes could only reach 8 banks -> 8-way
//   conflict; 16B-granular swizzle only permutes bank bits [4:2]).
//   Stage 2 (unchanged from R4): waves 0-3 q, 4-7 k, 8-15 v from LDS;
//   outputs qT/kT[b][n][oc], vblk[b][n>>4][oc][n&15] (attn formats).
// ---------------------------------------------------------------------------
__global__ __launch_bounds__(1024) void fconv_kernel(
    const float* __restrict__ x, const us* __restrict__ wqc,
    const us* __restrict__ wkc, const float* __restrict__ bq,
    const float* __restrict__ bk, const us* __restrict__ wvb,
    const float* __restrict__ bv, us* __restrict__ qT, us* __restrict__ kT,
    us* __restrict__ vblk) {
  __shared__ __align__(16) us xs[256 * 256];  // 128KB, swizzled [rr][c]

  int tid = threadIdx.x, lane = tid & 63, w = tid >> 6;
  int l15 = lane & 15, quad = lane >> 4;
  int l31 = lane & 31, h32 = lane >> 5;
  int hw = blockIdx.x;
  int b = hw & 7, yt = hw >> 3;  // XCD k owns batch k (8 XCDs, round-robin)
  int no0 = yt * 128;            // first own row (global n) of this block
  const float* xb = x + ((size_t)b << 20);

  // ---- stage 1: transpose into swizzled LDS (b128 writes) ----
  {
    int cw = w * 2 + h32;  // chunk column 0..31 (8 channels each)
    const float* xc = xb + ((size_t)(cw * 8) << 12);
#pragma unroll
    for (int it = 0; it < 8; it++) {
      int rr = it * 32 + l31;
      int gn = no0 - 64 + rr;
      bool valid = (unsigned)gn < 4096u;
      float a0 = valid ? xc[gn] : 0.f;
      float a1 = valid ? xc[(1 << 12) + gn] : 0.f;
      float a2 = valid ? xc[(2 << 12) + gn] : 0.f;
      float a3 = valid ? xc[(3 << 12) + gn] : 0.f;
      float a4 = valid ? xc[(4 << 12) + gn] : 0.f;
      float a5 = valid ? xc[(5 << 12) + gn] : 0.f;
      float a6 = valid ? xc[(6 << 12) + gn] : 0.f;
      float a7 = valid ? xc[(7 << 12) + gn] : 0.f;
      unsigned u0, u1, u2, u3;
      asm("v_cvt_pk_bf16_f32 %0, %1, %2" : "=v"(u0) : "v"(a0), "v"(a1));
      asm("v_cvt_pk_bf16_f32 %0, %1, %2" : "=v"(u1) : "v"(a2), "v"(a3));
      asm("v_cvt_pk_bf16_f32 %0, %1, %2" : "=v"(u2) : "v"(a4), "v"(a5));
      asm("v_cvt_pk_bf16_f32 %0, %1, %2" : "=v"(u3) : "v"(a6), "v"(a7));
      int chunk = cw ^ (rr & 31);
      *(uint4*)&xs[rr * 256 + chunk * 8] = make_uint4(u0, u1, u2, u3);
    }
  }
  __syncthreads();

  // ---- stage 2: convs from LDS ----
  if (w < 8) {
    bool isq = (w < 4);
    int qw = isq ? w : (w - 4);
    const us* wc = isq ? wqc : wkc;
    f32x4 acc00 = (f32x4){0.f, 0.f, 0.f, 0.f}, acc01 = acc00;
    f32x4 acc10 = acc00, acc11 = acc00;
#pragma unroll
    for (int t = 0; t < 3; t++) {
      int dn = isq ? (t - 1) : (t - 1) * 64;
#pragma unroll
      for (int k8 = 0; k8 < 8; k8++) {
        int kloc = t * 256 + k8 * 32 + quad * 8;
        bf16x8 af0 = *(const bf16x8*)(wc + (size_t)l15 * 768 + kloc);
        bf16x8 af1 = *(const bf16x8*)(wc + (size_t)(16 + l15) * 768 + kloc);
        int cb3 = (k8 * 32 + quad * 8) >> 3;
#pragma unroll
        for (int j = 0; j < 2; j++) {
          int ntl = (qw * 2 + j) * 16 + l15;
          int rr = 64 + ntl + dn;
          bf16x8 bf = *(const bf16x8*)&xs[rr * 256 + ((cb3 ^ (rr & 31)) << 3)];
          if (isq && ((t == 0 && (ntl & 63) == 0) || (t == 2 && (ntl & 63) == 63)))
            bf = (bf16x8){0, 0, 0, 0, 0, 0, 0, 0};
          if (j == 0) {
            acc00 = __builtin_amdgcn_mfma_f32_16x16x32_bf16(af0, bf, acc00, 0, 0, 0);
            acc10 = __builtin_amdgcn_mfma_f32_16x16x32_bf16(af1, bf, acc10, 0, 0, 0);
          } else {
            acc01 = __builtin_amdgcn_mfma_f32_16x16x32_bf16(af0, bf, acc01, 0, 0, 0);
            acc11 = __builtin_amdgcn_mfma_f32_16x16x32_bf16(af1, bf, acc11, 0, 0, 0);
          }
        }
      }
    }
    const float* bias = isq ? bq : bk;
    float bsc = isq ? LOG2E : 1.0f;
    us* outp = (isq ? qT : kT) + (((size_t)b << 12) * 32);
#pragma unroll
    for (int mo = 0; mo < 2; mo++) {
      float b0 = bias[mo * 16 + quad * 4 + 0] * bsc;
      float b1 = bias[mo * 16 + quad * 4 + 1] * bsc;
      float b2 = bias[mo * 16 + quad * 4 + 2] * bsc;
      float b3 = bias[mo * 16 + quad * 4 + 3] * bsc;
#pragma unroll
      for (int j = 0; j < 2; j++) {
        f32x4 a = (mo == 0) ? (j == 0 ? acc00 : acc01) : (j == 0 ? acc10 : acc11);
        int n = no0 + (qw * 2 + j) * 16 + l15;
        unsigned lo = (unsigned)f2bf(a[0] + b0) | ((unsigned)f2bf(a[1] + b1) << 16);
        unsigned hi = (unsigned)f2bf(a[2] + b2) | ((unsigned)f2bf(a[3] + b3) << 16);
        *(uint2*)(outp + (size_t)n * 32 + mo * 16 + quad * 4) = make_uint2(lo, hi);
      }
    }
  } else {
    int nt = w - 8;
    int rr = 64 + nt * 16 + l15;
    f32x4 acc[16];
#pragma unroll
    for (int ot = 0; ot < 16; ot++) acc[ot] = (f32x4){0.f, 0.f, 0.f, 0.f};
#pragma unroll
    for (int kk = 0; kk < 8; kk++) {
      int cb3 = (kk * 32 + quad * 8) >> 3;
      bf16x8 bfr = *(const bf16x8*)&xs[rr * 256 + ((cb3 ^ (rr & 31)) << 3)];
#pragma unroll
      for (int ot = 0; ot < 16; ot++) {
        bf16x8 af = *(const bf16x8*)(wvb + (size_t)(ot * 16 + l15) * 256 + kk * 32 + quad * 8);
        acc[ot] = __builtin_amdgcn_mfma_f32_16x16x32_bf16(af, bfr, acc[ot], 0, 0, 0);
      }
    }
    us* vb = vblk + ((size_t)b << 20);
    int n16 = yt * 8 + nt;
#pragma unroll
    for (int ot = 0; ot < 16; ot++) {
#pragma unroll
      for (int r = 0; r < 4; r++) {
        int oc = ot * 16 + quad * 4 + r;
        vb[((size_t)n16 * 256 + oc) * 16 + l15] = f2bf(acc[ot][r] + bv[oc]);
      }
    }
  }
}

// ---------------------------------------------------------------------------
// Flash attention (unchanged from R3/R4): no-max softmax, swapped QK,
// packed cvt_pk P-writes, T15 reorder, register ping-pong K/V prefetch,
// lgkmcnt-only barrier drain.
// ---------------------------------------------------------------------------
__global__ __launch_bounds__(512, 4) void attn_kernel(
    const float* __restrict__ x, const us* __restrict__ qT,
    const us* __restrict__ kT, const us* __restrict__ vblk,
    const float* __restrict__ gamma_p, float* __restrict__ out) {
  __shared__ __align__(16) us pb[2][64 * 72];  // [i][j], stride 72
  __shared__ float lpart[2][64];

  int tid = threadIdx.x, lane = tid & 63, w = tid >> 6;
  int l15 = lane & 15, quad = lane >> 4;
  int l31 = lane & 31, h32 = lane >> 5;
  int tw = w & 3, jh = w >> 2;

  int bid = blockIdx.x;
  int b = bid & 7, i0 = (bid >> 3) * 64;

  const us* qTb = qT + (((size_t)b << 12) * 32);
  const us* kTb = kT + (((size_t)b << 12) * 32);
  const us* vbb = vblk + ((size_t)b << 20);

  bf16x8 qf = *(const bf16x8*)(qTb + (size_t)(i0 + tw * 16 + l15) * 32 + quad * 8);

  const us* kbase = kTb + (size_t)(jh * 32 + l15) * 32 + quad * 8;   // +jt*2048
  const us* vbase = vbb + (size_t)(w * 32 + l31) * 16 + h32 * 8;     // +jt*16384
  int pwi = (tw * 16 + l15) * 72 + jh * 32 + quad * 4;
  int pri = l31 * 72 + h32 * 8;

  float lr = 0.f;
  f32x4 s0, s1;
  f32x16 o0, o1;
#pragma unroll
  for (int rg = 0; rg < 16; rg++) { o0[rg] = 0.f; o1[rg] = 0.f; }

  bf16x8 kS0a, kS0b, kS1a, kS1b;
  bf16x8 v0_0, v0_1, v0_2, v0_3;
  bf16x8 v1_0, v1_1, v1_2, v1_3;
  bf16x8 v2_0, v2_1, v2_2, v2_3;
  bf16x8 v3_0, v3_1, v3_2, v3_3;

#define PRE(JT, KN0, KN1, VN0, VN1, VN2, VN3)                                  \
  do {                                                                         \
    int jn = (JT) & 63;                                                        \
    const us* kp = kbase + (size_t)jn * 2048;                                  \
    const us* vp = vbase + (size_t)jn * 16384;                                 \
    KN0 = *(const bf16x8*)(kp);                                                \
    KN1 = *(const bf16x8*)(kp + 512);                                          \
    VN0 = *(const bf16x8*)(vp);                                                \
    VN1 = *(const bf16x8*)(vp + 4096);                                         \
    VN2 = *(const bf16x8*)(vp + 8192);                                         \
    VN3 = *(const bf16x8*)(vp + 12288);                                        \
  } while (0)

#define QKM(KC0, KC1)                                                          \
  do {                                                                         \
    s0 = __builtin_amdgcn_mfma_f32_16x16x32_bf16(KC0, qf, (f32x4){0.f, 0.f, 0.f, 0.f}, 0, 0, 0); \
    s1 = __builtin_amdgcn_mfma_f32_16x16x32_bf16(KC1, qf, (f32x4){0.f, 0.f, 0.f, 0.f}, 0, 0, 0); \
  } while (0)

#define PVM(BUFR, VP0, VP1, VP2, VP3)                                          \
  do {                                                                         \
    const us* pr = (const us*)pb + (BUFR) * (64 * 72) + pri;                   \
    __builtin_amdgcn_s_setprio(1);                                             \
    bf16x8 pf0, pf1;                                                           \
    pf0 = *(const bf16x8*)(pr + 0);                                            \
    pf1 = *(const bf16x8*)(pr + 32 * 72 + 0);                                  \
    o0 = __builtin_amdgcn_mfma_f32_32x32x16_bf16(VP0, pf0, o0, 0, 0, 0);       \
    o1 = __builtin_amdgcn_mfma_f32_32x32x16_bf16(VP0, pf1, o1, 0, 0, 0);       \
    pf0 = *(const bf16x8*)(pr + 16);                                           \
    pf1 = *(const bf16x8*)(pr + 32 * 72 + 16);                                 \
    o0 = __builtin_amdgcn_mfma_f32_32x32x16_bf16(VP1, pf0, o0, 0, 0, 0);       \
    o1 = __builtin_amdgcn_mfma_f32_32x32x16_bf16(VP1, pf1, o1, 0, 0, 0);       \
    pf0 = *(const bf16x8*)(pr + 32);                                           \
    pf1 = *(const bf16x8*)(pr + 32 * 72 + 32);                                 \
    o0 = __builtin_amdgcn_mfma_f32_32x32x16_bf16(VP2, pf0, o0, 0, 0, 0);       \
    o1 = __builtin_amdgcn_mfma_f32_32x32x16_bf16(VP2, pf1, o1, 0, 0, 0);       \
    pf0 = *(const bf16x8*)(pr + 48);                                           \
    pf1 = *(const bf16x8*)(pr + 32 * 72 + 48);                                 \
    o0 = __builtin_amdgcn_mfma_f32_32x32x16_bf16(VP3, pf0, o0, 0, 0, 0);       \
    o1 = __builtin_amdgcn_mfma_f32_32x32x16_bf16(VP3, pf1, o1, 0, 0, 0);       \
    __builtin_amdgcn_s_setprio(0);                                             \
  } while (0)

#define SMW(BUFW)                                                              \
  do {                                                                         \
    us* pw = (us*)pb + (BUFW) * (64 * 72) + pwi;                               \
    {                                                                          \
      float p0 = __builtin_amdgcn_exp2f(s0[0]);                                \
      float p1 = __builtin_amdgcn_exp2f(s0[1]);                                \
      float p2 = __builtin_amdgcn_exp2f(s0[2]);                                \
      float p3 = __builtin_amdgcn_exp2f(s0[3]);                                \
      lr += (p0 + p1) + (p2 + p3);                                             \
      unsigned e0, e1;                                                         \
      asm("v_cvt_pk_bf16_f32 %0, %1, %2" : "=v"(e0) : "v"(p0), "v"(p1));       \
      asm("v_cvt_pk_bf16_f32 %0, %1, %2" : "=v"(e1) : "v"(p2), "v"(p3));       \
      *(uint2*)pw = make_uint2(e0, e1);                                        \
    }                                                                          \
    {                                                                          \
      float p0 = __builtin_amdgcn_exp2f(s1[0]);                                \
      float p1 = __builtin_amdgcn_exp2f(s1[1]);                                \
      float p2 = __builtin_amdgcn_exp2f(s1[2]);                                \
      float p3 = __builtin_amdgcn_exp2f(s1[3]);                                \
      lr += (p0 + p1) + (p2 + p3);                                             \
      unsigned e0, e1;                                                         \
      asm("v_cvt_pk_bf16_f32 %0, %1, %2" : "=v"(e0) : "v"(p0), "v"(p1));       \
      asm("v_cvt_pk_bf16_f32 %0, %1, %2" : "=v"(e1) : "v"(p2), "v"(p3));       \
      *(uint2*)(pw + 16) = make_uint2(e0, e1);                                 \
    }                                                                          \
  } while (0)

#define BAR                                                                    \
  do {                                                                         \
    asm volatile("s_waitcnt lgkmcnt(0)" ::: "memory");                         \
    __builtin_amdgcn_s_barrier();                                              \
    __builtin_amdgcn_sched_barrier(0);                                         \
  } while (0)

  PRE(0, kS0a, kS0b, v0_0, v0_1, v0_2, v0_3);
  PRE(1, kS1a, kS1b, v1_0, v1_1, v1_2, v1_3);
  QKM(kS0a, kS0b);
  SMW(0);
  BAR;
  PRE(2, kS0a, kS0b, v2_0, v2_1, v2_2, v2_3);
  QKM(kS1a, kS1b);
  PVM(0, v0_0, v0_1, v0_2, v0_3);
  SMW(1);
  BAR;
  PRE(3, kS1a, kS1b, v3_0, v3_1, v3_2, v3_3);
  QKM(kS0a, kS0b);
  PVM(1, v1_0, v1_1, v1_2, v1_3);
  SMW(0);
  BAR;
  PRE(4, kS0a, kS0b, v0_0, v0_1, v0_2, v0_3);
  QKM(kS1a, kS1b);
  PVM(0, v2_0, v2_1, v2_2, v2_3);
  SMW(1);
  BAR;

  for (int n4 = 1; n4 < 16; n4++) {
    int n = n4 * 4;
    PRE(n + 1, kS1a, kS1b, v1_0, v1_1, v1_2, v1_3);
    QKM(kS0a, kS0b);
    PVM(1, v3_0, v3_1, v3_2, v3_3);
    SMW(0);
    BAR;
    PRE(n + 2, kS0a, kS0b, v2_0, v2_1, v2_2, v2_3);
    QKM(kS1a, kS1b);
    PVM(0, v0_0, v0_1, v0_2, v0_3);
    SMW(1);
    BAR;
    PRE(n + 3, kS1a, kS1b, v3_0, v3_1, v3_2, v3_3);
    QKM(kS0a, kS0b);
    PVM(1, v1_0, v1_1, v1_2, v1_3);
    SMW(0);
    BAR;
    PRE(n + 4, kS0a, kS0b, v0_0, v0_1, v0_2, v0_3);
    QKM(kS1a, kS1b);
    PVM(0, v2_0, v2_1, v2_2, v2_3);
    SMW(1);
    BAR;
  }
  PVM(1, v3_0, v3_1, v3_2, v3_3);

#undef PRE
#undef QKM
#undef PVM
#undef SMW
#undef BAR

  float lt = lr;
  lt += __shfl_xor(lt, 16);
  lt += __shfl_xor(lt, 32);
  if (quad == 0) lpart[jh][tw * 16 + l15] = lt;
  __syncthreads();
  float g = gamma_p[0];
  const float* xb = x + ((size_t)b << 20);
  float* ob = out + ((size_t)b << 20);
  float gl[2];
#pragma unroll
  for (int it = 0; it < 2; it++) {
    int i = it * 32 + l31;
    gl[it] = g / (lpart[0][i] + lpart[1][i]);
  }
#pragma unroll
  for (int it = 0; it < 2; it++) {
    int i = i0 + it * 32 + l31;
    const f32x16& o = (it == 0) ? o0 : o1;
#pragma unroll
    for (int rg = 0; rg < 16; rg++) {
      int c = w * 32 + ((rg & 3) + 8 * (rg >> 2) + 4 * h32);
      size_t idx = ((size_t)c << 12) + i;
      ob[idx] = o[rg] * gl[it] + xb[idx];
    }
  }
}

// ---------------------------------------------------------------------------
extern "C" void kernel_launch(void* const* d_in, const int* in_sizes, int n_in,
                              void* d_out, int out_size, void* d_ws, size_t ws_size,
                              hipStream_t stream) {
  const float* x = (const float*)d_in[0];
  const float* wq = (const float*)d_in[1];
  const float* bq = (const float*)d_in[2];
  const float* wk = (const float*)d_in[3];
  const float* bk = (const float*)d_in[4];
  const float* wv = (const float*)d_in[5];
  const float* bv = (const float*)d_in[6];
  const float* gamma = (const float*)d_in[7];
  float* out = (float*)d_out;

  us* qT = (us*)d_ws;                 // 1,048,576 us
  us* kT = qT + (size_t)1048576;      // 1,048,576
  us* vblk = kT + (size_t)1048576;    // 8,388,608
  us* wqc = vblk + (size_t)8388608;   // 24,576
  us* wkc = wqc + (size_t)24576;      // 24,576
  us* wvb = wkc + (size_t)24576;      // 65,536

  wrep_kernel<<<448, 256, 0, stream>>>(wq, wk, wv, wqc, wkc, wvb);
  fconv_kernel<<<256, 1024, 0, stream>>>(x, wqc, wkc, bq, bk, wvb, bv, qT, kT, vblk);
  attn_kernel<<<512, 512, 0, stream>>>(x, qT, kT, vblk, gamma, out);
}

// Round 6
// 231.173 us; speedup vs baseline: 1.0349x; 1.0198x over previous
//
#include <hip/hip_runtime.h>
#include <math.h>

#define LOG2E 1.44269504f

typedef unsigned short us;
typedef __attribute__((ext_vector_type(8))) short bf16x8;
typedef __attribute__((ext_vector_type(4))) float f32x4;
typedef __attribute__((ext_vector_type(16))) float f32x16;

static __device__ __forceinline__ us f2bf(float f) {  // RNE
  union { float f; unsigned u; } v; v.f = f;
  unsigned r = v.u + 0x7fffu + ((v.u >> 16) & 1u);
  return (us)(r >> 16);
}

// ---------------------------------------------------------------------------
// prep_kernel (R3 known-best): blocks 0..2047: transpose x f32 -> xT bf16.
//              blocks 2048..2495: weight repack (wq*LOG2E, wk im2col, wv).
// ---------------------------------------------------------------------------
__global__ __launch_bounds__(256) void prep_kernel(
    const float* __restrict__ x, const float* __restrict__ wq,
    const float* __restrict__ wk, const float* __restrict__ wv,
    us* __restrict__ xT, us* __restrict__ wqc, us* __restrict__ wkc,
    us* __restrict__ wvb) {
  __shared__ __align__(16) us lt[64 * 68];
  int bid = blockIdx.x;
  int tid = threadIdx.x;
  if (bid < 2048) {
    int b = bid >> 8, cb = (bid >> 6) & 3, nb = bid & 63;
    const float* xb = x + (((size_t)(b * 256 + cb * 64)) << 12);
    int nl = tid & 63, ch = tid >> 6;
#pragma unroll
    for (int p = 0; p < 16; p++) {
      int c = p * 4 + ch;
      lt[nl * 68 + c] = f2bf(xb[((size_t)c << 12) + (nb * 64 + nl)]);
    }
    __syncthreads();
    us* xTb = xT + (((size_t)b << 12) + nb * 64) * 256 + cb * 64;
    int cw = tid & 7, nr0 = tid >> 3;
#pragma unroll
    for (int p2 = 0; p2 < 2; p2++) {
      int nr = p2 * 32 + nr0;
      uint2 lo = *(const uint2*)&lt[nr * 68 + cw * 8];
      uint2 hi = *(const uint2*)&lt[nr * 68 + cw * 8 + 4];
      *(uint4*)&xTb[(size_t)nr * 256 + cw * 8] = make_uint4(lo.x, lo.y, hi.x, hi.y);
    }
  } else {
    int idx = (bid - 2048) * 256 + tid;
    if (idx < 24576) {
      int oc = idx / 768, r = idx % 768, t = r >> 8, ic = r & 255;
      wqc[idx] = f2bf(wq[(oc * 256 + ic) * 3 + t] * LOG2E);
    } else if (idx < 49152) {
      int j = idx - 24576;
      int oc = j / 768, r = j % 768, t = r >> 8, ic = r & 255;
      wkc[j] = f2bf(wk[(oc * 256 + ic) * 3 + t]);
    } else if (idx < 114688) {
      int j = idx - 49152;
      wvb[j] = f2bf(wv[j]);
    }
  }
}

// ---------------------------------------------------------------------------
// conv_kernel (R3 known-best): blocks 0..511 q/k convs; 512..1023 v conv.
// ---------------------------------------------------------------------------
__global__ __launch_bounds__(256) void conv_kernel(
    const us* __restrict__ xT, const us* __restrict__ wqc,
    const us* __restrict__ wkc, const float* __restrict__ bq,
    const float* __restrict__ bk, const us* __restrict__ wvb,
    const float* __restrict__ bv, us* __restrict__ qT, us* __restrict__ kT,
    us* __restrict__ vblk) {
  int tid = threadIdx.x, lane = tid & 63, w = tid >> 6;
  int l15 = lane & 15, quad = lane >> 4;
  if (blockIdx.x < 512) {
    int bid = blockIdx.x;
    int b = bid & 7, rt = bid >> 3;
    int n0 = rt * 64, y = rt;
    bool isq = (w < 2);
    int m0 = (w & 1) * 16;
    const us* wc = isq ? wqc : wkc;
    const us* xTb = xT + (((size_t)b << 12) * 256);
    f32x4 acc[4];
#pragma unroll
    for (int nt = 0; nt < 4; nt++) acc[nt] = (f32x4){0.f, 0.f, 0.f, 0.f};
#pragma unroll
    for (int t = 0; t < 3; t++) {
      bool killT = (!isq) && ((t == 0 && y == 0) || (t == 2 && y == 63));
      if (!killT) {
        int dn = isq ? (t - 1) : (t - 1) * 64;
#pragma unroll
        for (int k8 = 0; k8 < 8; k8++) {
          int kloc = t * 256 + k8 * 32 + quad * 8;
          bf16x8 af = *(const bf16x8*)(wc + (size_t)(m0 + l15) * 768 + kloc);
          int ic = k8 * 32 + quad * 8;
#pragma unroll
          for (int nt = 0; nt < 4; nt++) {
            int nl = nt * 16 + l15;
            int ns = n0 + nl + dn;
            ns = ns < 0 ? 0 : (ns > 4095 ? 4095 : ns);
            bf16x8 bf = *(const bf16x8*)(xTb + (size_t)ns * 256 + ic);
            if (isq && ((t == 0 && nl == 0) || (t == 2 && nl == 63)))
              bf = (bf16x8){0, 0, 0, 0, 0, 0, 0, 0};
            acc[nt] = __builtin_amdgcn_mfma_f32_16x16x32_bf16(af, bf, acc[nt], 0, 0, 0);
          }
        }
      }
    }
    const float* bias = isq ? bq : bk;
    float bsc = isq ? LOG2E : 1.0f;
    us* outp = (isq ? qT : kT) + (((size_t)b << 12) * 32);
    float b0 = bias[m0 + quad * 4 + 0] * bsc;
    float b1 = bias[m0 + quad * 4 + 1] * bsc;
    float b2 = bias[m0 + quad * 4 + 2] * bsc;
    float b3 = bias[m0 + quad * 4 + 3] * bsc;
#pragma unroll
    for (int nt = 0; nt < 4; nt++) {
      int n = n0 + nt * 16 + l15;
      unsigned lo = (unsigned)f2bf(acc[nt][0] + b0) | ((unsigned)f2bf(acc[nt][1] + b1) << 16);
      unsigned hi = (unsigned)f2bf(acc[nt][2] + b2) | ((unsigned)f2bf(acc[nt][3] + b3) << 16);
      *(uint2*)(outp + (size_t)n * 32 + m0 + quad * 4) = make_uint2(lo, hi);
    }
  } else {
    int bid = blockIdx.x - 512;
    int b = bid & 7, nt0 = bid >> 3;
    int n0 = nt0 * 64;
    const us* xTb = xT + (((size_t)b << 12) * 256);
    f32x4 acc[4][4];  // [ct][nt]
#pragma unroll
    for (int ct = 0; ct < 4; ct++)
#pragma unroll
      for (int nt = 0; nt < 4; nt++) acc[ct][nt] = (f32x4){0.f, 0.f, 0.f, 0.f};
#pragma unroll
    for (int kk = 0; kk < 8; kk++) {
      bf16x8 bfr[4];
#pragma unroll
      for (int nt = 0; nt < 4; nt++)
        bfr[nt] = *(const bf16x8*)(xTb + (size_t)(n0 + nt * 16 + l15) * 256 + kk * 32 + quad * 8);
#pragma unroll
      for (int ct = 0; ct < 4; ct++) {
        bf16x8 af = *(const bf16x8*)(wvb + (size_t)(w * 64 + ct * 16 + l15) * 256 + kk * 32 + quad * 8);
#pragma unroll
        for (int nt = 0; nt < 4; nt++)
          acc[ct][nt] = __builtin_amdgcn_mfma_f32_16x16x32_bf16(af, bfr[nt], acc[ct][nt], 0, 0, 0);
      }
    }
    us* vb = vblk + ((size_t)b << 20);
#pragma unroll
    for (int ct = 0; ct < 4; ct++) {
#pragma unroll
      for (int r = 0; r < 4; r++) {
        int oc = w * 64 + ct * 16 + quad * 4 + r;
        float bvv = bv[oc];
#pragma unroll
        for (int nt = 0; nt < 4; nt++) {
          vb[((size_t)((n0 >> 4) + nt) * 256 + oc) * 16 + l15] = f2bf(acc[ct][nt][r] + bvv);
        }
      }
    }
  }
}

// ---------------------------------------------------------------------------
// Flash attention, 128-j steps (32 iters, ONE barrier per 128 j — halves the
// rendezvous overhead that was 37% of step time). Swapped QK mfma(k,q): 4
// MFMAs -> s0..s3; 16 exp2 + 8 cvt_pk + 4 b64 P-writes (stride 136 us,
// same benign 2-way bank structure as old stride 72). V: single register
// set, loads issued right after QK, landing hidden under softmax+barrier;
// K ping-ponged one iter ahead. Double-buffered P, 1 barrier/iter:
// buf[n&1] written at n, read at n after BAR; the lgkmcnt(0) at n+1 drains
// iter-n PV reads before any wave can rewrite that buffer at n+2.
// grid 512 = 8b * 64 i-tiles; 2 blocks/CU; same-b blocks share one XCD.
// ---------------------------------------------------------------------------
__global__ __launch_bounds__(512, 4) void attn_kernel(
    const float* __restrict__ x, const us* __restrict__ qT,
    const us* __restrict__ kT, const us* __restrict__ vblk,
    const float* __restrict__ gamma_p, float* __restrict__ out) {
  __shared__ __align__(16) us pb[2][64 * 136];  // [i][j0..127], stride 136
  __shared__ float lpart[2][64];

  int tid = threadIdx.x, lane = tid & 63, w = tid >> 6;
  int l15 = lane & 15, quad = lane >> 4;
  int l31 = lane & 31, h32 = lane >> 5;
  int tw = w & 3, jh = w >> 2;

  int bid = blockIdx.x;
  int b = bid & 7, i0 = (bid >> 3) * 64;

  const us* qTb = qT + (((size_t)b << 12) * 32);
  const us* kTb = kT + (((size_t)b << 12) * 32);
  const us* vbb = vblk + ((size_t)b << 20);

  bf16x8 qf = *(const bf16x8*)(qTb + (size_t)(i0 + tw * 16 + l15) * 32 + quad * 8);

  // per-thread invariant addresses (us units)
  const us* kbase = kTb + (size_t)(jh * 64 + l15) * 32 + quad * 8;  // +c*512 +n*4096
  const us* vbase = vbb + (size_t)(w * 32 + l31) * 16 + h32 * 8;    // +ks*4096 +n*32768
  int pwi = (tw * 16 + l15) * 136 + jh * 64 + quad * 4;  // [i][j' = jh*64+c*16+quad*4]
  int pri = l31 * 136 + h32 * 8;                         // PV read base

  float lr = 0.f;
  f32x4 s0, s1, s2, s3;
  f32x16 o0, o1;  // c-tile = w*32, i-tile = it*32
#pragma unroll
  for (int rg = 0; rg < 16; rg++) { o0[rg] = 0.f; o1[rg] = 0.f; }

  bf16x8 kX0, kX1, kX2, kX3, kY0, kY1, kY2, kY3;  // K ping-pong (4 frags/set)
  bf16x8 vf0, vf1, vf2, vf3, vf4, vf5, vf6, vf7;  // V single set

#define PREK(N, K0, K1, K2, K3)                                                \
  do {                                                                         \
    const us* kp = kbase + (size_t)((N) & 31) * 4096;                          \
    K0 = *(const bf16x8*)(kp);                                                 \
    K1 = *(const bf16x8*)(kp + 512);                                           \
    K2 = *(const bf16x8*)(kp + 1024);                                          \
    K3 = *(const bf16x8*)(kp + 1536);                                          \
  } while (0)

#define PREV(N)                                                                \
  do {                                                                         \
    const us* vp = vbase + (size_t)((N) & 31) * 32768;                         \
    vf0 = *(const bf16x8*)(vp);                                                \
    vf1 = *(const bf16x8*)(vp + 4096);                                         \
    vf2 = *(const bf16x8*)(vp + 8192);                                         \
    vf3 = *(const bf16x8*)(vp + 12288);                                        \
    vf4 = *(const bf16x8*)(vp + 16384);                                        \
    vf5 = *(const bf16x8*)(vp + 20480);                                        \
    vf6 = *(const bf16x8*)(vp + 24576);                                        \
    vf7 = *(const bf16x8*)(vp + 28672);                                        \
  } while (0)

#define QKM(K0, K1, K2, K3)                                                    \
  do {                                                                         \
    __builtin_amdgcn_s_setprio(1);                                             \
    s0 = __builtin_amdgcn_mfma_f32_16x16x32_bf16(K0, qf, (f32x4){0.f, 0.f, 0.f, 0.f}, 0, 0, 0); \
    s1 = __builtin_amdgcn_mfma_f32_16x16x32_bf16(K1, qf, (f32x4){0.f, 0.f, 0.f, 0.f}, 0, 0, 0); \
    s2 = __builtin_amdgcn_mfma_f32_16x16x32_bf16(K2, qf, (f32x4){0.f, 0.f, 0.f, 0.f}, 0, 0, 0); \
    s3 = __builtin_amdgcn_mfma_f32_16x16x32_bf16(K3, qf, (f32x4){0.f, 0.f, 0.f, 0.f}, 0, 0, 0); \
    __builtin_amdgcn_s_setprio(0);                                             \
  } while (0)

#define SMW1(SR, PWOFF)                                                        \
  do {                                                                         \
    float p0 = __builtin_amdgcn_exp2f(SR[0]);                                  \
    float p1 = __builtin_amdgcn_exp2f(SR[1]);                                  \
    float p2 = __builtin_amdgcn_exp2f(SR[2]);                                  \
    float p3 = __builtin_amdgcn_exp2f(SR[3]);                                  \
    lr += (p0 + p1) + (p2 + p3);                                               \
    unsigned e0, e1;                                                           \
    asm("v_cvt_pk_bf16_f32 %0, %1, %2" : "=v"(e0) : "v"(p0), "v"(p1));         \
    asm("v_cvt_pk_bf16_f32 %0, %1, %2" : "=v"(e1) : "v"(p2), "v"(p3));         \
    *(uint2*)(pw + (PWOFF)) = make_uint2(e0, e1);                              \
  } while (0)

#define SMW(BUF)                                                               \
  do {                                                                         \
    us* pw = (us*)pb + (BUF) * (64 * 136) + pwi;                               \
    SMW1(s0, 0);                                                               \
    SMW1(s1, 16);                                                              \
    SMW1(s2, 32);                                                              \
    SMW1(s3, 48);                                                              \
  } while (0)

#define BAR                                                                    \
  do {                                                                         \
    asm volatile("s_waitcnt lgkmcnt(0)" ::: "memory");                         \
    __builtin_amdgcn_s_barrier();                                              \
    __builtin_amdgcn_sched_barrier(0);                                         \
  } while (0)

#define PV1(VF, KSOFF)                                                         \
  do {                                                                         \
    bf16x8 pf0 = *(const bf16x8*)(pr + (KSOFF));                               \
    bf16x8 pf1 = *(const bf16x8*)(pr + 32 * 136 + (KSOFF));                    \
    o0 = __builtin_amdgcn_mfma_f32_32x32x16_bf16(VF, pf0, o0, 0, 0, 0);        \
    o1 = __builtin_amdgcn_mfma_f32_32x32x16_bf16(VF, pf1, o1, 0, 0, 0);        \
  } while (0)

#define PVM(BUF)                                                               \
  do {                                                                         \
    const us* pr = (const us*)pb + (BUF) * (64 * 136) + pri;                   \
    __builtin_amdgcn_s_setprio(1);                                             \
    PV1(vf0, 0);                                                               \
    PV1(vf1, 16);                                                              \
    PV1(vf2, 32);                                                              \
    PV1(vf3, 48);                                                              \
    PV1(vf4, 64);                                                              \
    PV1(vf5, 80);                                                              \
    PV1(vf6, 96);                                                              \
    PV1(vf7, 112);                                                             \
    __builtin_amdgcn_s_setprio(0);                                             \
  } while (0)

  PREK(0, kX0, kX1, kX2, kX3);
  for (int n2 = 0; n2 < 16; n2++) {
    int n = n2 * 2;
    // even iter: kc = X, buf 0
    QKM(kX0, kX1, kX2, kX3);
    PREV(n);
    PREK(n + 1, kY0, kY1, kY2, kY3);
    SMW(0);
    BAR;
    PVM(0);
    // odd iter: kc = Y, buf 1
    QKM(kY0, kY1, kY2, kY3);
    PREV(n + 1);
    PREK(n + 2, kX0, kX1, kX2, kX3);
    SMW(1);
    BAR;
    PVM(1);
  }

#undef PREK
#undef PREV
#undef QKM
#undef SMW1
#undef SMW
#undef BAR
#undef PV1
#undef PVM

  // ---- final l: lane (l15,quad) holds partial over its j-subset at i=l15;
  //      reduce across quads (lane^16, lane^32), combine jh halves via LDS ----
  float lt = lr;
  lt += __shfl_xor(lt, 16);
  lt += __shfl_xor(lt, 32);
  if (quad == 0) lpart[jh][tw * 16 + l15] = lt;
  __syncthreads();
  float g = gamma_p[0];
  const float* xb = x + ((size_t)b << 20);
  float* ob = out + ((size_t)b << 20);
  float gl[2];
#pragma unroll
  for (int it = 0; it < 2; it++) {
    int i = it * 32 + l31;
    gl[it] = g / (lpart[0][i] + lpart[1][i]);
  }
#pragma unroll
  for (int it = 0; it < 2; it++) {
    int i = i0 + it * 32 + l31;
    const f32x16& o = (it == 0) ? o0 : o1;
#pragma unroll
    for (int rg = 0; rg < 16; rg++) {
      int c = w * 32 + ((rg & 3) + 8 * (rg >> 2) + 4 * h32);
      size_t idx = ((size_t)c << 12) + i;
      ob[idx] = o[rg] * gl[it] + xb[idx];
    }
  }
}

// ---------------------------------------------------------------------------
extern "C" void kernel_launch(void* const* d_in, const int* in_sizes, int n_in,
                              void* d_out, int out_size, void* d_ws, size_t ws_size,
                              hipStream_t stream) {
  const float* x = (const float*)d_in[0];
  const float* wq = (const float*)d_in[1];
  const float* bq = (const float*)d_in[2];
  const float* wk = (const float*)d_in[3];
  const float* bk = (const float*)d_in[4];
  const float* wv = (const float*)d_in[5];
  const float* bv = (const float*)d_in[6];
  const float* gamma = (const float*)d_in[7];
  float* out = (float*)d_out;

  us* xT = (us*)d_ws;                 // 8,388,608
  us* qT = xT + (size_t)8388608;      // 1,048,576
  us* kT = qT + (size_t)1048576;      // 1,048,576
  us* vblk = kT + (size_t)1048576;    // 8,388,608
  us* wqc = vblk + (size_t)8388608;   // 24,576
  us* wkc = wqc + (size_t)24576;      // 24,576
  us* wvb = wkc + (size_t)24576;      // 65,536

  prep_kernel<<<2496, 256, 0, stream>>>(x, wq, wk, wv, xT, wqc, wkc, wvb);
  conv_kernel<<<1024, 256, 0, stream>>>(xT, wqc, wkc, bq, bk, wvb, bv, qT, kT, vblk);
  attn_kernel<<<512, 512, 0, stream>>>(x, qT, kT, vblk, gamma, out);
}